// Round 1
// baseline (111.969 us; speedup 1.0000x reference)
//
#include <hip/hip_runtime.h>

#define HH 512
#define WW 512
#define NB 8
#define NC 128
#define ROWS 4

// ws layout: [0,16) two float accumulators (scale_sum, hm_sum); [16, 16+NB*NC*16) float4 params
// params per center: {s = 1/(sigma*sqrt(2)), o = -cx*s, p = -cy*s, pad}

__global__ void ahl_prep_kernel(const float* __restrict__ pred_sm,
                                const float* __restrict__ ground_res,
                                const int* __restrict__ centers,
                                float4* __restrict__ params,
                                float* __restrict__ acc) {
    int b = blockIdx.x;
    int n = threadIdx.x;
    if (b == 0 && n < 2) acc[n] = 0.0f;   // zero accumulators (ws is poisoned 0xAA)
    int cy = centers[(b * NC + n) * 2 + 0];
    int cx = centers[(b * NC + n) * 2 + 1];
    cy = min(max(cy, 0), HH - 1);
    cx = min(max(cx, 0), WW - 1);
    float sm = pred_sm[(size_t)b * HH * WW + (size_t)cy * WW + cx];
    float g = ground_res[b];
    // sizes = PR_MIN/gr + relu(sm)*REF_GROUND_RES/gr ; PR_MIN = REF_GROUND_RES = 0.2
    float size = 0.2f / g + fmaxf(sm, 0.0f) * (0.2f / g);
    float inv = 1.0f / (2.0f * size * size);
    float s = sqrtf(inv);
    params[b * NC + n] = make_float4(s, -(float)cx * s, -(float)cy * s, 0.0f);
}

__global__ __launch_bounds__(256) void ahl_main_kernel(
    const float* __restrict__ pred_hm,
    const float* __restrict__ pred_sm,
    const float* __restrict__ mask,
    const float4* __restrict__ params,
    float* __restrict__ out,            // out[0]=sl, out[1]=hl, gts at out+2
    float* __restrict__ acc) {
    __shared__ float4 sp[NC];
    __shared__ float red[8];
    const int blocksPerSample = HH / ROWS;            // 128
    const int b  = blockIdx.x / blocksPerSample;
    const int y0 = (blockIdx.x % blocksPerSample) * ROWS;
    const int tid = threadIdx.x;

    if (tid < NC) sp[tid] = params[b * NC + tid];
    __syncthreads();

    const float x0f = (float)tid;
    const float x1f = (float)(tid + 256);
    float yf[ROWS];
#pragma unroll
    for (int r = 0; r < ROWS; r++) yf[r] = (float)(y0 + r);

    float m[ROWS][2];
#pragma unroll
    for (int r = 0; r < ROWS; r++) { m[r][0] = 1e30f; m[r][1] = 1e30f; }

    // min over centers of scaled squared distance; gt = exp(-min)
    for (int n = 0; n < NC; n++) {
        float4 P = sp[n];
        float dxs0 = fmaf(x0f, P.x, P.y);
        float dxs1 = fmaf(x1f, P.x, P.y);
        float dx2_0 = dxs0 * dxs0;
        float dx2_1 = dxs1 * dxs1;
#pragma unroll
        for (int r = 0; r < ROWS; r++) {
            float dys = fmaf(yf[r], P.x, P.z);
            float a = dys * dys;
            m[r][0] = fminf(m[r][0], dx2_0 + a);
            m[r][1] = fminf(m[r][1], dx2_1 + a);
        }
    }

    // epilogue: write gts, accumulate losses
    float lhm = 0.0f, lsc = 0.0f;
    const size_t base = (size_t)b * HH * WW + (size_t)y0 * WW;
#pragma unroll
    for (int r = 0; r < ROWS; r++) {
#pragma unroll
        for (int p = 0; p < 2; p++) {
            int x = tid + p * 256;
            size_t idx = base + (size_t)r * WW + x;
            float gt = __expf(-m[r][p]);
            out[2 + idx] = gt;
            float hm = pred_hm[idx];
            float mk = mask[idx];
            float sm = pred_sm[idx];
            float d = hm - gt;
            lhm = fmaf(d * d, mk, lhm);
            lsc = fmaf(sm, sm, lsc);
        }
    }

    // wave (64-lane) reduction then cross-wave via LDS
#pragma unroll
    for (int off = 32; off > 0; off >>= 1) {
        lhm += __shfl_down(lhm, off);
        lsc += __shfl_down(lsc, off);
    }
    int lane = tid & 63, wid = tid >> 6;
    if (lane == 0) { red[wid] = lhm; red[4 + wid] = lsc; }
    __syncthreads();
    if (tid == 0) {
        float th = red[0] + red[1] + red[2] + red[3];
        float ts = red[4] + red[5] + red[6] + red[7];
        atomicAdd(&acc[0], ts);   // scale_loss sum
        atomicAdd(&acc[1], th);   // hm_loss sum
    }
}

__global__ void ahl_finalize_kernel(const float* __restrict__ acc,
                                    float* __restrict__ out) {
    const float invc = 1.0f / (float)((size_t)NB * HH * WW);
    out[0] = acc[0] * invc;
    out[1] = acc[1] * invc;
}

extern "C" void kernel_launch(void* const* d_in, const int* in_sizes, int n_in,
                              void* d_out, int out_size, void* d_ws, size_t ws_size,
                              hipStream_t stream) {
    const float* pred_hm    = (const float*)d_in[0];
    const float* pred_sm    = (const float*)d_in[1];
    const float* ground_res = (const float*)d_in[2];
    const float* mask       = (const float*)d_in[3];
    const int*   centers    = (const int*)d_in[4];
    float* out = (float*)d_out;

    float*  acc    = (float*)d_ws;                       // 2 floats used
    float4* params = (float4*)((char*)d_ws + 16);        // NB*NC float4 = 16 KB

    ahl_prep_kernel<<<NB, NC, 0, stream>>>(pred_sm, ground_res, centers, params, acc);
    ahl_main_kernel<<<NB * (HH / ROWS), 256, 0, stream>>>(pred_hm, pred_sm, mask,
                                                          params, out, acc);
    ahl_finalize_kernel<<<1, 1, 0, stream>>>(acc, out);
}

// Round 2
// 86.408 us; speedup vs baseline: 1.2958x; 1.2958x over previous
//
#include <hip/hip_runtime.h>

#define HH 512
#define WW 512
#define NB 8
#define NC 128
#define TW 64          // tile width
#define TH 64          // tile height
#define TILES_X (WW / TW)   // 8
#define TILES_Y (HH / TH)   // 8
#define NTILES (TILES_X * TILES_Y)  // 64
#define CUT 30.0f      // exp(-30) ~ 9e-14 << 2e-2 tolerance

// ws layout: per-block partial sums, float2 {scale_sum, hm_sum} per block.
// Every block writes its slot, so no zero-init needed (ws is poisoned 0xAA).

__global__ __launch_bounds__(256) void ahl_main_kernel(
    const float* __restrict__ pred_hm,
    const float* __restrict__ pred_sm,
    const float* __restrict__ mask,
    const float* __restrict__ ground_res,
    const int*   __restrict__ centers,
    float* __restrict__ out,            // out[0]=sl, out[1]=hl, gts at out+2
    float2* __restrict__ partials) {
    __shared__ float4 sp[NC];   // all params {s, o=-cx*s, p=-cy*s, _}
    __shared__ float4 sc[NC];   // culled params for this tile
    __shared__ int s_cnt;
    __shared__ float red[8];

    const int b    = blockIdx.x >> 6;          // /NTILES
    const int tile = blockIdx.x & 63;
    const int tx0  = (tile & 7) * TW;
    const int ty0  = (tile >> 3) * TH;
    const int tid  = threadIdx.x;

    // ---- phase 0: per-center params (redundant per block; gathers are L2-hot)
    if (tid == 0) s_cnt = 0;
    if (tid < NC) {
        int cy = centers[(b * NC + tid) * 2 + 0];
        int cx = centers[(b * NC + tid) * 2 + 1];
        cy = min(max(cy, 0), HH - 1);
        cx = min(max(cx, 0), WW - 1);
        float sm = pred_sm[(size_t)b * HH * WW + (size_t)cy * WW + cx];
        float g  = ground_res[b];
        // size = 0.2/g * (1 + relu(sm));  inv = 1/(2 size^2);  s = sqrt(inv)
        float size = (0.2f / g) * (1.0f + fmaxf(sm, 0.0f));
        float s = 0.70710678f / size;          // sqrt(1/(2 size^2))
        sp[tid] = make_float4(s, -(float)cx * s, -(float)cy * s, 0.0f);
    }
    __syncthreads();

    // ---- phase 1: cull centers vs this tile's rect (scaled distance)
    if (tid < NC) {
        float4 P = sp[tid];
        float a0 = fmaf((float)tx0,            P.x, P.y);   // (tx0-cx)*s
        float a1 = fmaf((float)(tx0 + TW - 1), P.x, P.y);   // (tx1-cx)*s
        float b0 = fmaf((float)ty0,            P.x, P.z);
        float b1 = fmaf((float)(ty0 + TH - 1), P.x, P.z);
        float dx = fmaxf(0.0f, fmaxf(a0, -a1));
        float dy = fmaxf(0.0f, fmaxf(b0, -b1));
        if (fmaf(dx, dx, dy * dy) < CUT) {
            int i = atomicAdd(&s_cnt, 1);
            sc[i] = P;
        }
    }
    __syncthreads();
    const int cnt = s_cnt;

    // ---- phase 2: min-splat over culled centers
    // thread covers 2 cols (tid&31, +32) x 8 rows ((tid>>5) + r*8)
    const float c0f = (float)(tx0 + (tid & 31));
    const float c1f = c0f + 32.0f;
    const int   rb  = ty0 + (tid >> 5);
    float rf[8];
#pragma unroll
    for (int r = 0; r < 8; r++) rf[r] = (float)(rb + r * 8);

    float m0[8], m1[8];
#pragma unroll
    for (int r = 0; r < 8; r++) { m0[r] = 1e30f; m1[r] = 1e30f; }

    for (int i = 0; i < cnt; i++) {
        float4 P = sc[i];
        float dxs0 = fmaf(c0f, P.x, P.y);
        float dxs1 = fmaf(c1f, P.x, P.y);
        float dx20 = dxs0 * dxs0;
        float dx21 = dxs1 * dxs1;
#pragma unroll
        for (int r = 0; r < 8; r++) {
            float dys = fmaf(rf[r], P.x, P.z);
            float a = dys * dys;
            m0[r] = fminf(m0[r], dx20 + a);
            m1[r] = fminf(m1[r], dx21 + a);
        }
    }

    // ---- phase 3: epilogue — write gts, accumulate losses
    float lhm = 0.0f, lsc = 0.0f;
    const size_t sbase = (size_t)b * HH * WW;
    const int col0 = tx0 + (tid & 31);
#pragma unroll
    for (int r = 0; r < 8; r++) {
        size_t rowbase = sbase + (size_t)(rb + r * 8) * WW;
#pragma unroll
        for (int p = 0; p < 2; p++) {
            size_t idx = rowbase + col0 + p * 32;
            float gt = __expf(-(p == 0 ? m0[r] : m1[r]));
            out[2 + idx] = gt;
            float hm = pred_hm[idx];
            float mk = mask[idx];
            float sm = pred_sm[idx];
            float d = hm - gt;
            lhm = fmaf(d * d, mk, lhm);
            lsc = fmaf(sm, sm, lsc);
        }
    }

    // wave reduce then cross-wave
#pragma unroll
    for (int off = 32; off > 0; off >>= 1) {
        lhm += __shfl_down(lhm, off);
        lsc += __shfl_down(lsc, off);
    }
    int lane = tid & 63, wid = tid >> 6;
    if (lane == 0) { red[wid] = lsc; red[4 + wid] = lhm; }
    __syncthreads();
    if (tid == 0) {
        float ts = red[0] + red[1] + red[2] + red[3];
        float th = red[4] + red[5] + red[6] + red[7];
        partials[blockIdx.x] = make_float2(ts, th);
    }
}

__global__ __launch_bounds__(256) void ahl_reduce_kernel(
    const float2* __restrict__ partials, float* __restrict__ out) {
    __shared__ float red[8];
    const int tid = threadIdx.x;
    float2 a = partials[tid];
    float2 c = partials[tid + 256];
    float ts = a.x + c.x;
    float th = a.y + c.y;
#pragma unroll
    for (int off = 32; off > 0; off >>= 1) {
        ts += __shfl_down(ts, off);
        th += __shfl_down(th, off);
    }
    int lane = tid & 63, wid = tid >> 6;
    if (lane == 0) { red[wid] = ts; red[4 + wid] = th; }
    __syncthreads();
    if (tid == 0) {
        const float invc = 1.0f / (float)((size_t)NB * HH * WW);
        out[0] = (red[0] + red[1] + red[2] + red[3]) * invc;
        out[1] = (red[4] + red[5] + red[6] + red[7]) * invc;
    }
}

extern "C" void kernel_launch(void* const* d_in, const int* in_sizes, int n_in,
                              void* d_out, int out_size, void* d_ws, size_t ws_size,
                              hipStream_t stream) {
    const float* pred_hm    = (const float*)d_in[0];
    const float* pred_sm    = (const float*)d_in[1];
    const float* ground_res = (const float*)d_in[2];
    const float* mask       = (const float*)d_in[3];
    const int*   centers    = (const int*)d_in[4];
    float* out = (float*)d_out;
    float2* partials = (float2*)d_ws;   // NB*NTILES = 512 float2

    ahl_main_kernel<<<NB * NTILES, 256, 0, stream>>>(pred_hm, pred_sm, mask,
                                                     ground_res, centers, out,
                                                     partials);
    ahl_reduce_kernel<<<1, 256, 0, stream>>>(partials, out);
}